// Round 5
// baseline (352.428 us; speedup 1.0000x reference)
//
#include <hip/hip_runtime.h>

#define BLOCK  256
#define CHUNK  (BLOCK * 2)   // 2 points per thread

// clang native vector: valid for __builtin_nontemporal_load, same layout as float4
typedef float f4 __attribute__((ext_vector_type(4)));

// Per-point GICP mahalanobis: maha = res^T * adj(RCR) * res / det(RCR)
// RCR = C_tar[idx] + T3 * C_src * T3^T  (3x3 symmetric SPD)
// Fully scalar-named unroll-by-2: no per-thread arrays -> no scratch.
__global__ __launch_bounds__(BLOCK, 4) void gicp_maha_kernel(
    const float* __restrict__ T,
    const f4*    __restrict__ src,
    const f4*    __restrict__ tar,
    const f4*    __restrict__ cs,
    const f4*    __restrict__ ct,
    const int*   __restrict__ idx,
    float*       __restrict__ partial,  // [gridDim.x], each written once
    int n)
{
    const float t00 = T[0],  t01 = T[1],  t02 = T[2];
    const float t10 = T[4],  t11 = T[5],  t12 = T[6];
    const float t20 = T[8],  t21 = T[9],  t22 = T[10];
    const float t30 = T[12], t31 = T[13], t32 = T[14];

    const int i0r = blockIdx.x * CHUNK + threadIdx.x;
    const int i1r = i0r + BLOCK;
    const bool v0 = (i0r < n);
    const bool v1 = (i1r < n);
    const int i0 = v0 ? i0r : 0;
    const int i1 = v1 ? i1r : 0;

    // --- issue long-latency index loads first ---
    const int j0 = __builtin_nontemporal_load(idx + i0);
    const int j1 = __builtin_nontemporal_load(idx + i1);

    // --- streaming loads (independent of idx; overlap with idx latency) ---
    const f4 s0 = __builtin_nontemporal_load(src + i0);
    const f4 s1 = __builtin_nontemporal_load(src + i1);
    const size_t b0 = (size_t)i0 * 4;
    const size_t b1 = (size_t)i1 * 4;
    const f4 a00 = __builtin_nontemporal_load(cs + b0 + 0);
    const f4 a01 = __builtin_nontemporal_load(cs + b0 + 1);
    const f4 a02 = __builtin_nontemporal_load(cs + b0 + 2);
    const f4 a10 = __builtin_nontemporal_load(cs + b1 + 0);
    const f4 a11 = __builtin_nontemporal_load(cs + b1 + 1);
    const f4 a12 = __builtin_nontemporal_load(cs + b1 + 2);

    // --- gathers (need j0/j1; vmcnt is in-order so this only waits on idx) ---
    const size_t g0 = (size_t)j0 * 4;
    const size_t g1 = (size_t)j1 * 4;
    const f4 tp0 = tar[j0];
    const f4 e00 = ct[g0 + 0];
    const f4 e01 = ct[g0 + 1];
    const f4 e02 = ct[g0 + 2];
    const f4 tp1 = tar[j1];
    const f4 e10 = ct[g1 + 0];
    const f4 e11 = ct[g1 + 1];
    const f4 e12 = ct[g1 + 2];

    // ---------------- point 0 ----------------
    float m0, m1;
    {
        const float ts0 = s0.x*t00 + s0.y*t10 + s0.z*t20 + s0.w*t30;
        const float ts1 = s0.x*t01 + s0.y*t11 + s0.z*t21 + s0.w*t31;
        const float ts2 = s0.x*t02 + s0.y*t12 + s0.z*t22 + s0.w*t32;
        const float r0 = tp0.x - ts0;
        const float r1 = tp0.y - ts1;
        const float r2 = tp0.z - ts2;

        const float u00 = t00*a00.x + t01*a01.x + t02*a02.x;
        const float u01 = t00*a00.y + t01*a01.y + t02*a02.y;
        const float u02 = t00*a00.z + t01*a01.z + t02*a02.z;
        const float u10 = t10*a00.x + t11*a01.x + t12*a02.x;
        const float u11 = t10*a00.y + t11*a01.y + t12*a02.y;
        const float u12 = t10*a00.z + t11*a01.z + t12*a02.z;
        const float u20 = t20*a00.x + t21*a01.x + t22*a02.x;
        const float u21 = t20*a00.y + t21*a01.y + t22*a02.y;
        const float u22 = t20*a00.z + t21*a01.z + t22*a02.z;

        const float a = e00.x + u00*t00 + u01*t01 + u02*t02;
        const float b = e00.y + u00*t10 + u01*t11 + u02*t12;
        const float c = e00.z + u00*t20 + u01*t21 + u02*t22;
        const float d = e01.y + u10*t10 + u11*t11 + u12*t12;
        const float e = e01.z + u10*t20 + u11*t21 + u12*t22;
        const float f = e02.z + u20*t20 + u21*t21 + u22*t22;

        const float A00 = d*f - e*e;
        const float A01 = c*e - b*f;
        const float A02 = b*e - c*d;
        const float A11 = a*f - c*c;
        const float A12 = b*c - a*e;
        const float A22 = a*d - b*b;
        const float det = a*A00 + b*A01 + c*A02;
        const float num = r0*r0*A00 + r1*r1*A11 + r2*r2*A22
                        + 2.0f*(r0*r1*A01 + r0*r2*A02 + r1*r2*A12);
        m0 = num / det;
    }
    // ---------------- point 1 ----------------
    {
        const float ts0 = s1.x*t00 + s1.y*t10 + s1.z*t20 + s1.w*t30;
        const float ts1 = s1.x*t01 + s1.y*t11 + s1.z*t21 + s1.w*t31;
        const float ts2 = s1.x*t02 + s1.y*t12 + s1.z*t22 + s1.w*t32;
        const float r0 = tp1.x - ts0;
        const float r1 = tp1.y - ts1;
        const float r2 = tp1.z - ts2;

        const float u00 = t00*a10.x + t01*a11.x + t02*a12.x;
        const float u01 = t00*a10.y + t01*a11.y + t02*a12.y;
        const float u02 = t00*a10.z + t01*a11.z + t02*a12.z;
        const float u10 = t10*a10.x + t11*a11.x + t12*a12.x;
        const float u11 = t10*a10.y + t11*a11.y + t12*a12.y;
        const float u12 = t10*a10.z + t11*a11.z + t12*a12.z;
        const float u20 = t20*a10.x + t21*a11.x + t22*a12.x;
        const float u21 = t20*a10.y + t21*a11.y + t22*a12.y;
        const float u22 = t20*a10.z + t21*a11.z + t22*a12.z;

        const float a = e10.x + u00*t00 + u01*t01 + u02*t02;
        const float b = e10.y + u00*t10 + u01*t11 + u02*t12;
        const float c = e10.z + u00*t20 + u01*t21 + u02*t22;
        const float d = e11.y + u10*t10 + u11*t11 + u12*t12;
        const float e = e11.z + u10*t20 + u11*t21 + u12*t22;
        const float f = e12.z + u20*t20 + u21*t21 + u22*t22;

        const float A00 = d*f - e*e;
        const float A01 = c*e - b*f;
        const float A02 = b*e - c*d;
        const float A11 = a*f - c*c;
        const float A12 = b*c - a*e;
        const float A22 = a*d - b*b;
        const float det = a*A00 + b*A01 + c*A02;
        const float num = r0*r0*A00 + r1*r1*A11 + r2*r2*A22
                        + 2.0f*(r0*r1*A01 + r0*r2*A02 + r1*r2*A12);
        m1 = num / det;
    }

    float local = (v0 ? m0 : 0.0f) + (v1 ? m1 : 0.0f);

    // wave-64 reduction, then one LDS slot per wave, one store per block
    for (int off = 32; off > 0; off >>= 1)
        local += __shfl_down(local, off, 64);

    __shared__ float wsum[BLOCK / 64];
    const int wave = threadIdx.x >> 6;
    if ((threadIdx.x & 63) == 0) wsum[wave] = local;
    __syncthreads();
    if (threadIdx.x == 0) {
        float s = wsum[0];
        #pragma unroll
        for (int w = 1; w < BLOCK / 64; ++w) s += wsum[w];
        partial[blockIdx.x] = s;
    }
}

__global__ __launch_bounds__(256) void gicp_finalize_kernel(
    const float* __restrict__ partial, float* __restrict__ out,
    int nblocks, double scale)
{
    double s = 0.0;
    for (int k = threadIdx.x; k < nblocks; k += 256)
        s += (double)partial[k];
    for (int off = 32; off > 0; off >>= 1)
        s += __shfl_down(s, off, 64);
    __shared__ double wsum[4];
    const int wave = threadIdx.x >> 6;
    if ((threadIdx.x & 63) == 0) wsum[wave] = s;
    __syncthreads();
    if (threadIdx.x == 0)
        out[0] = (float)((wsum[0] + wsum[1] + wsum[2] + wsum[3]) * scale);
}

extern "C" void kernel_launch(void* const* d_in, const int* in_sizes, int n_in,
                              void* d_out, int out_size, void* d_ws, size_t ws_size,
                              hipStream_t stream) {
    const float* T   = (const float*)d_in[0];
    const f4*    src = (const f4*)d_in[1];
    const f4*    tar = (const f4*)d_in[2];
    const f4*    cs  = (const f4*)d_in[3];
    const f4*    ct  = (const f4*)d_in[4];
    const int*   idx = (const int*)d_in[5];
    const int n = in_sizes[1] / 4;  // src_points is (N,4)

    const int grid = (n + CHUNK - 1) / CHUNK;   // 3907 for n=2e6
    float* partial = (float*)d_ws;              // grid floats, fully overwritten

    gicp_maha_kernel<<<grid, BLOCK, 0, stream>>>(T, src, tar, cs, ct, idx,
                                                 partial, n);
    gicp_finalize_kernel<<<1, 256, 0, stream>>>(partial, (float*)d_out,
                                                grid, 0.5 / (double)n);
}

// Round 6
// 339.606 us; speedup vs baseline: 1.0378x; 1.0378x over previous
//
#include <hip/hip_runtime.h>

#define BLOCK  256
#define CHUNK  (BLOCK * 2)   // 2 points per thread

typedef float f4 __attribute__((ext_vector_type(4)));

// Per-point GICP mahalanobis: maha = res^T * adj(RCR) * res / det(RCR)
// RCR = C_tar[idx] + T3 * C_src * T3^T  (3x3 symmetric SPD)
// Unroll-by-2 with named scalars (no arrays -> no scratch). Plain loads:
// R2 vs R5 counters showed default caching gives minimal HBM traffic (328 MB);
// nontemporal added +68 MB of gather-repeat misses.
__global__ __launch_bounds__(BLOCK, 4) void gicp_maha_kernel(
    const float* __restrict__ T,
    const f4*    __restrict__ src,
    const f4*    __restrict__ tar,
    const f4*    __restrict__ cs,
    const f4*    __restrict__ ct,
    const int*   __restrict__ idx,
    float*       __restrict__ partial,  // [gridDim.x], each written once
    int n)
{
    const float t00 = T[0],  t01 = T[1],  t02 = T[2];
    const float t10 = T[4],  t11 = T[5],  t12 = T[6];
    const float t20 = T[8],  t21 = T[9],  t22 = T[10];
    const float t30 = T[12], t31 = T[13], t32 = T[14];

    const int i0r = blockIdx.x * CHUNK + threadIdx.x;
    const int i1r = i0r + BLOCK;
    const bool v0 = (i0r < n);
    const bool v1 = (i1r < n);
    const int i0 = v0 ? i0r : 0;
    const int i1 = v1 ? i1r : 0;

    // --- long-latency index loads first ---
    const int j0 = idx[i0];
    const int j1 = idx[i1];

    // --- streaming loads (independent of idx; overlap with idx latency) ---
    const f4 s0 = src[i0];
    const f4 s1 = src[i1];
    const size_t b0 = (size_t)i0 * 4;
    const size_t b1 = (size_t)i1 * 4;
    const f4 a00 = cs[b0 + 0];
    const f4 a01 = cs[b0 + 1];
    const f4 a02 = cs[b0 + 2];
    const f4 a10 = cs[b1 + 0];
    const f4 a11 = cs[b1 + 1];
    const f4 a12 = cs[b1 + 2];

    // --- gathers (need j0/j1) ---
    const size_t g0 = (size_t)j0 * 4;
    const size_t g1 = (size_t)j1 * 4;
    const f4 tp0 = tar[j0];
    const f4 e00 = ct[g0 + 0];
    const f4 e01 = ct[g0 + 1];
    const f4 e02 = ct[g0 + 2];
    const f4 tp1 = tar[j1];
    const f4 e10 = ct[g1 + 0];
    const f4 e11 = ct[g1 + 1];
    const f4 e12 = ct[g1 + 2];

    // ---------------- point 0 ----------------
    float m0, m1;
    {
        const float ts0 = s0.x*t00 + s0.y*t10 + s0.z*t20 + s0.w*t30;
        const float ts1 = s0.x*t01 + s0.y*t11 + s0.z*t21 + s0.w*t31;
        const float ts2 = s0.x*t02 + s0.y*t12 + s0.z*t22 + s0.w*t32;
        const float r0 = tp0.x - ts0;
        const float r1 = tp0.y - ts1;
        const float r2 = tp0.z - ts2;

        const float u00 = t00*a00.x + t01*a01.x + t02*a02.x;
        const float u01 = t00*a00.y + t01*a01.y + t02*a02.y;
        const float u02 = t00*a00.z + t01*a01.z + t02*a02.z;
        const float u10 = t10*a00.x + t11*a01.x + t12*a02.x;
        const float u11 = t10*a00.y + t11*a01.y + t12*a02.y;
        const float u12 = t10*a00.z + t11*a01.z + t12*a02.z;
        const float u20 = t20*a00.x + t21*a01.x + t22*a02.x;
        const float u21 = t20*a00.y + t21*a01.y + t22*a02.y;
        const float u22 = t20*a00.z + t21*a01.z + t22*a02.z;

        const float a = e00.x + u00*t00 + u01*t01 + u02*t02;
        const float b = e00.y + u00*t10 + u01*t11 + u02*t12;
        const float c = e00.z + u00*t20 + u01*t21 + u02*t22;
        const float d = e01.y + u10*t10 + u11*t11 + u12*t12;
        const float e = e01.z + u10*t20 + u11*t21 + u12*t22;
        const float f = e02.z + u20*t20 + u21*t21 + u22*t22;

        const float A00 = d*f - e*e;
        const float A01 = c*e - b*f;
        const float A02 = b*e - c*d;
        const float A11 = a*f - c*c;
        const float A12 = b*c - a*e;
        const float A22 = a*d - b*b;
        const float det = a*A00 + b*A01 + c*A02;
        const float num = r0*r0*A00 + r1*r1*A11 + r2*r2*A22
                        + 2.0f*(r0*r1*A01 + r0*r2*A02 + r1*r2*A12);
        m0 = num / det;
    }
    // ---------------- point 1 ----------------
    {
        const float ts0 = s1.x*t00 + s1.y*t10 + s1.z*t20 + s1.w*t30;
        const float ts1 = s1.x*t01 + s1.y*t11 + s1.z*t21 + s1.w*t31;
        const float ts2 = s1.x*t02 + s1.y*t12 + s1.z*t22 + s1.w*t32;
        const float r0 = tp1.x - ts0;
        const float r1 = tp1.y - ts1;
        const float r2 = tp1.z - ts2;

        const float u00 = t00*a10.x + t01*a11.x + t02*a12.x;
        const float u01 = t00*a10.y + t01*a11.y + t02*a12.y;
        const float u02 = t00*a10.z + t01*a11.z + t02*a12.z;
        const float u10 = t10*a10.x + t11*a11.x + t12*a12.x;
        const float u11 = t10*a10.y + t11*a11.y + t12*a12.y;
        const float u12 = t10*a10.z + t11*a11.z + t12*a12.z;
        const float u20 = t20*a10.x + t21*a11.x + t22*a12.x;
        const float u21 = t20*a10.y + t21*a11.y + t22*a12.y;
        const float u22 = t20*a10.z + t21*a11.z + t22*a12.z;

        const float a = e10.x + u00*t00 + u01*t01 + u02*t02;
        const float b = e10.y + u00*t10 + u01*t11 + u02*t12;
        const float c = e10.z + u00*t20 + u01*t21 + u02*t22;
        const float d = e11.y + u10*t10 + u11*t11 + u12*t12;
        const float e = e11.z + u10*t20 + u11*t21 + u12*t22;
        const float f = e12.z + u20*t20 + u21*t21 + u22*t22;

        const float A00 = d*f - e*e;
        const float A01 = c*e - b*f;
        const float A02 = b*e - c*d;
        const float A11 = a*f - c*c;
        const float A12 = b*c - a*e;
        const float A22 = a*d - b*b;
        const float det = a*A00 + b*A01 + c*A02;
        const float num = r0*r0*A00 + r1*r1*A11 + r2*r2*A22
                        + 2.0f*(r0*r1*A01 + r0*r2*A02 + r1*r2*A12);
        m1 = num / det;
    }

    float local = (v0 ? m0 : 0.0f) + (v1 ? m1 : 0.0f);

    // wave-64 reduction, then one LDS slot per wave, one store per block
    for (int off = 32; off > 0; off >>= 1)
        local += __shfl_down(local, off, 64);

    __shared__ float wsum[BLOCK / 64];
    const int wave = threadIdx.x >> 6;
    if ((threadIdx.x & 63) == 0) wsum[wave] = local;
    __syncthreads();
    if (threadIdx.x == 0) {
        float s = wsum[0];
        #pragma unroll
        for (int w = 1; w < BLOCK / 64; ++w) s += wsum[w];
        partial[blockIdx.x] = s;
    }
}

__global__ __launch_bounds__(256) void gicp_finalize_kernel(
    const float* __restrict__ partial, float* __restrict__ out,
    int nblocks, double scale)
{
    double s = 0.0;
    for (int k = threadIdx.x; k < nblocks; k += 256)
        s += (double)partial[k];
    for (int off = 32; off > 0; off >>= 1)
        s += __shfl_down(s, off, 64);
    __shared__ double wsum[4];
    const int wave = threadIdx.x >> 6;
    if ((threadIdx.x & 63) == 0) wsum[wave] = s;
    __syncthreads();
    if (threadIdx.x == 0)
        out[0] = (float)((wsum[0] + wsum[1] + wsum[2] + wsum[3]) * scale);
}

extern "C" void kernel_launch(void* const* d_in, const int* in_sizes, int n_in,
                              void* d_out, int out_size, void* d_ws, size_t ws_size,
                              hipStream_t stream) {
    const float* T   = (const float*)d_in[0];
    const f4*    src = (const f4*)d_in[1];
    const f4*    tar = (const f4*)d_in[2];
    const f4*    cs  = (const f4*)d_in[3];
    const f4*    ct  = (const f4*)d_in[4];
    const int*   idx = (const int*)d_in[5];
    const int n = in_sizes[1] / 4;  // src_points is (N,4)

    const int grid = (n + CHUNK - 1) / CHUNK;   // 3907 for n=2e6
    float* partial = (float*)d_ws;              // grid floats, fully overwritten

    gicp_maha_kernel<<<grid, BLOCK, 0, stream>>>(T, src, tar, cs, ct, idx,
                                                 partial, n);
    gicp_finalize_kernel<<<1, 256, 0, stream>>>(partial, (float*)d_out,
                                                grid, 0.5 / (double)n);
}